// Round 8
// baseline (347.512 us; speedup 1.0000x reference)
//
#include <hip/hip_runtime.h>
#include <hip/hip_bf16.h>
#include <math.h>

// ---------------------------------------------------------------------------
// GAT 3-layer forward.
// R19: SCAT_B 256 -> 1024. R18's fused scatter ran on only 256 blocks ->
// 12 serial atomic round-trips/thread -> 63us tail with everything idle
// (VALU 6%, HBM 18%). 1024 blocks restores ~4x scatter MLP (~3 edges/thread)
// and still co-schedules with the 784 gemm tiles (~1280 resident slots).
// 1024 % 8 == 0 keeps gemm bid->XCD mapping. Everything else = R18.
// ---------------------------------------------------------------------------

#define NEG_SLOPE 0.2f
#define CAP_E 96
#define SCAT_B 1024

typedef __attribute__((ext_vector_type(8))) _Float16 v8h;  // 8 f16 in 4 VGPRs
typedef __attribute__((ext_vector_type(2))) _Float16 half2v;
typedef __attribute__((ext_vector_type(4))) float f32x4;

// ---------------- f16 helpers ----------------

__device__ __forceinline__ unsigned short f16_bits(float x) {
    _Float16 h = (_Float16)x;
    union { _Float16 h; unsigned short u; } c;
    c.h = h;
    return c.u;
}

__device__ __forceinline__ float f16_to_f32(unsigned short u) {
    union { _Float16 h; unsigned short u; } c;
    c.u = u;
    return (float)c.h;
}

// ---------------- prep: zero cnt + convert both weight matrices -----------

__global__ __launch_bounds__(256) void prep(const float* __restrict__ W0,
                                            unsigned short* __restrict__ t0,
                                            const float* __restrict__ W1,
                                            unsigned short* __restrict__ t1,
                                            int* __restrict__ cnt, int N) {
    int idx = blockIdx.x * 256 + threadIdx.x;
    if (idx < N) cnt[idx] = 0;
    int j0 = idx - N;
    if (j0 >= 0 && j0 < 128 * 256) {
        int f = j0 >> 8, k = j0 & 255;
        t0[k * 128 + f] = f16_bits(W0[j0]);
    }
    int j1 = idx - N - 128 * 256;
    if (j1 >= 0 && j1 < 256 * 256) {
        int f = j1 >> 8, k = j1 & 255;
        t1[k * 256 + f] = f16_bits(W1[j1]);
    }
}

// ---------------- f16 MFMA GEMM body (shared by layer 0 fused + layer 1) --
// bid remap: groups of 16 bids = 8 A-rows x 2 col-blocks (A-tile L2 reuse).
// AF32: A is fp32, converted to f16 during staging (layer 0).
// Epilogue: featb repacked via LDS (Cs overlays As/Bs) -> dwordx4 stores.

template <bool AF32>
__device__ __forceinline__ void gemm_body(int bid,
                                          const unsigned short* __restrict__ Af,
                                          const float* __restrict__ A32,
                                          const unsigned short* __restrict__ Bt,
                                          unsigned short* __restrict__ featb,
                                          float* __restrict__ el,
                                          float* __restrict__ er,
                                          const float* __restrict__ al,
                                          const float* __restrict__ ar,
                                          int N, int F, int K) {
    __shared__ unsigned short smem[2 * 128 * 40];  // As + Bs; Cs overlays
    auto As = (unsigned short (*)[40])smem;
    auto Bs = (unsigned short (*)[40])(smem + 128 * 40);
    auto Cs = (unsigned short (*)[136])smem;  // 64 x 136 (17.4KB <= 20.5KB)

    int tid = threadIdx.x;
    int lane = tid & 63, w = tid >> 6;
    int wr = (w >> 1) * 64, wc = (w & 1) * 64;
    int lr = lane & 15, lq = lane >> 4;
    int g = bid >> 4, b16 = bid & 15;
    int rowb = g * 8 + (b16 & 7);
    int colb = b16 >> 3;
    int m0 = rowb * 128, n0 = colb * 128;
    if (m0 >= N) return;  // padded row-blocks: whole block exits (uniform)
    f32x4 acc[4][4] = {};

    for (int k0 = 0; k0 < F; k0 += 32) {
        __syncthreads();
#pragma unroll
        for (int i = 0; i < 2; ++i) {
            int slot = i * 256 + tid;
            int r = slot >> 2, cc = slot & 3;
            int gr = m0 + r;
            uint4 v = make_uint4(0u, 0u, 0u, 0u);
            if (AF32) {
                if (gr < N) {
                    const float* p = &A32[(size_t)gr * F + k0 + cc * 8];
                    float4 f0 = *(const float4*)p;
                    float4 f1 = *(const float4*)(p + 4);
                    v.x = (unsigned)f16_bits(f0.x) | ((unsigned)f16_bits(f0.y) << 16);
                    v.y = (unsigned)f16_bits(f0.z) | ((unsigned)f16_bits(f0.w) << 16);
                    v.z = (unsigned)f16_bits(f1.x) | ((unsigned)f16_bits(f1.y) << 16);
                    v.w = (unsigned)f16_bits(f1.z) | ((unsigned)f16_bits(f1.w) << 16);
                }
            } else {
                if (gr < N) v = *(const uint4*)&Af[(size_t)gr * F + k0 + cc * 8];
            }
            *(uint4*)&As[r][cc * 8] = v;
        }
#pragma unroll
        for (int i = 0; i < 2; ++i) {
            int slot = i * 256 + tid;
            int r = slot >> 2, cc = slot & 3;
            uint4 bv = *(const uint4*)&Bt[(size_t)(n0 + r) * F + k0 + cc * 8];
            *(uint4*)&Bs[r][cc * 8] = bv;
        }
        __syncthreads();

        v8h af[4], bf[4];
#pragma unroll
        for (int mt = 0; mt < 4; ++mt)
            af[mt] = *(const v8h*)&As[wr + mt * 16 + lr][lq * 8];
#pragma unroll
        for (int nt = 0; nt < 4; ++nt)
            bf[nt] = *(const v8h*)&Bs[wc + nt * 16 + lr][lq * 8];
#pragma unroll
        for (int mt = 0; mt < 4; ++mt)
#pragma unroll
            for (int nt = 0; nt < 4; ++nt)
                acc[mt][nt] = __builtin_amdgcn_mfma_f32_16x16x32_f16(af[mt], bf[nt], acc[mt][nt], 0, 0, 0);
    }

    // ---- el/er epilogue (registers only) ----
    int h = (n0 + wc) >> 6;
    float alw[4], arw[4];
#pragma unroll
    for (int nt = 0; nt < 4; ++nt) {
        int d = nt * 16 + lr;
        alw[nt] = al[h * 64 + d];
        arw[nt] = ar[h * 64 + d];
    }
#pragma unroll
    for (int mt = 0; mt < 4; ++mt) {
#pragma unroll
        for (int r = 0; r < 4; ++r) {
            float se = 0.f, sr = 0.f;
#pragma unroll
            for (int nt = 0; nt < 4; ++nt) {
                float v = acc[mt][nt][r];
                se += v * alw[nt];
                sr += v * arw[nt];
            }
#pragma unroll
            for (int o = 8; o >= 1; o >>= 1) {
                se += __shfl_xor(se, o);
                sr += __shfl_xor(sr, o);
            }
            int row = m0 + wr + mt * 16 + lq * 4 + r;
            if (lr == 0 && row < N) {
                el[(size_t)row * 4 + h] = se;
                er[(size_t)row * 4 + h] = sr;
            }
        }
    }

    // ---- featb epilogue via LDS repack: 2 halves of 64 rows ----
#pragma unroll
    for (int half = 0; half < 2; ++half) {
        __syncthreads();
#pragma unroll
        for (int mtl = 0; mtl < 2; ++mtl) {
            int mt = half * 2 + mtl;
            int cr = (wr >> 1) + mtl * 16 + lq * 4;
#pragma unroll
            for (int nt = 0; nt < 4; ++nt) {
                int col = wc + nt * 16 + lr;
#pragma unroll
                for (int r = 0; r < 4; ++r)
                    Cs[cr + r][col] = f16_bits(acc[mt][nt][r]);
            }
        }
        __syncthreads();
        int cr = tid >> 2, seg = (tid & 3) * 32;
        int grow = m0 + (cr & 31) + ((cr >> 5) << 6) + half * 32;
        if (grow < N) {
            uint4* dst4 = (uint4*)&featb[(size_t)grow * K + n0 + seg];
            const uint4* src4 = (const uint4*)&Cs[cr][seg];
            dst4[0] = src4[0];
            dst4[1] = src4[1];
            dst4[2] = src4[2];
            dst4[3] = src4[3];
        }
    }
}

// ---------------- fused: edge scatter (blocks 0..SCAT_B-1) + layer-0 GEMM -

__global__ __launch_bounds__(256) void scatter_gemm0(const int* __restrict__ src,
                                                     const int* __restrict__ dst,
                                                     int* __restrict__ cnt,
                                                     int* __restrict__ csr, int E,
                                                     const float* __restrict__ A32,
                                                     const unsigned short* __restrict__ Bt,
                                                     unsigned short* __restrict__ featb,
                                                     float* __restrict__ el,
                                                     float* __restrict__ er,
                                                     const float* __restrict__ al,
                                                     const float* __restrict__ ar,
                                                     int N) {
    if (blockIdx.x < SCAT_B) {
        int stride = SCAT_B * 256;
        for (int e = blockIdx.x * 256 + threadIdx.x; e < E; e += stride) {
            int d = dst[e];
            int pos = atomicAdd(&cnt[d], 1);
            if (pos < CAP_E) csr[d * CAP_E + pos] = src[e];
        }
    } else {
        gemm_body<true>(blockIdx.x - SCAT_B, nullptr, A32, Bt, featb, el, er, al, ar, N, 128, 256);
    }
}

// ---------------- layer-1 GEMM ----------------

__global__ __launch_bounds__(256) void gemm_l1(const unsigned short* __restrict__ Af,
                                               const unsigned short* __restrict__ Bt,
                                               unsigned short* __restrict__ featb,
                                               float* __restrict__ el,
                                               float* __restrict__ er,
                                               const float* __restrict__ al,
                                               const float* __restrict__ ar,
                                               int N) {
    int bid = blockIdx.x + blockIdx.y * 2;
    gemm_body<false>(bid, Af, nullptr, Bt, featb, el, er, al, ar, N, 256, 256);
}

// ---------------- layer-2 GEMM via MFMA (K=16 out), W2 hi/lo split --------

__global__ __launch_bounds__(256) void gemm2_mfma(const unsigned short* __restrict__ Af,
                                                  const float* __restrict__ W,
                                                  const float* __restrict__ al2,
                                                  const float* __restrict__ ar2,
                                                  float* __restrict__ el,
                                                  float* __restrict__ er,
                                                  unsigned short* __restrict__ featb,
                                                  int N) {
    int tid = threadIdx.x;
    int wv = tid >> 6, lane = tid & 63;
    int lr = lane & 15, lq = lane >> 4;
    int m0 = blockIdx.x * 256 + wv * 64;
    if (m0 >= N) return;

    v8h bh[8], bl[8];
#pragma unroll
    for (int kk = 0; kk < 8; ++kk) {
#pragma unroll
        for (int j = 0; j < 8; ++j) {
            float wval = W[(kk * 32 + lq * 8 + j) * 16 + lr];
            _Float16 hi = (_Float16)wval;
            _Float16 lo = (_Float16)(wval - (float)hi);
            bh[kk][j] = hi;
            bl[kk][j] = lo;
        }
    }

    f32x4 acc[4] = {};
#pragma unroll
    for (int kk = 0; kk < 8; ++kk) {
        v8h af[4];
#pragma unroll
        for (int mt = 0; mt < 4; ++mt) {
            int row = m0 + mt * 16 + lr;
            v8h a = {};
            if (row < N) a = *(const v8h*)&Af[(size_t)row * 256 + kk * 32 + lq * 8];
            af[mt] = a;
        }
#pragma unroll
        for (int mt = 0; mt < 4; ++mt) {
            acc[mt] = __builtin_amdgcn_mfma_f32_16x16x32_f16(af[mt], bh[kk], acc[mt], 0, 0, 0);
            acc[mt] = __builtin_amdgcn_mfma_f32_16x16x32_f16(af[mt], bl[kk], acc[mt], 0, 0, 0);
        }
    }

    float alv = al2[lr], arv = ar2[lr];
#pragma unroll
    for (int mt = 0; mt < 4; ++mt) {
#pragma unroll
        for (int r = 0; r < 4; ++r) {
            int row = m0 + mt * 16 + lq * 4 + r;
            float v = acc[mt][r];
            float pe = v * alv, pr = v * arv;
            pe += __shfl_xor(pe, 1); pr += __shfl_xor(pr, 1);
            pe += __shfl_xor(pe, 2); pr += __shfl_xor(pr, 2);
            pe += __shfl_xor(pe, 4); pr += __shfl_xor(pr, 4);
            pe += __shfl_xor(pe, 8); pr += __shfl_xor(pr, 8);
            if (row < N) {
                if (lr == 0) { el[row] = pe; er[row] = pr; }
                featb[(size_t)row * 16 + lr] = f16_bits(v);
            }
        }
    }
}

// ---------------- agg for H=4, D=64: half-wave per node (R14 shape) -------

template <int U>
__global__ __launch_bounds__(256) void agg4_kernel(const unsigned short* __restrict__ featb,
                                                   const float* __restrict__ el,
                                                   const float* __restrict__ er,
                                                   const float* __restrict__ bias,
                                                   const int* __restrict__ cnt,
                                                   const int* __restrict__ csr,
                                                   unsigned short* __restrict__ outh, int N) {
    constexpr int CAP = 32;
    __shared__ float s_alpha[8][4][33];  // [halfwave][head][edge], 33-pad
    __shared__ int s_src[8][CAP];
    int hw = threadIdx.x >> 5;
    int cl = threadIdx.x & 31;
    int n = blockIdx.x * 8 + hw;
    if (n >= N) return;
    int begin = n * CAP_E;
    int deg = cnt[n];
    deg = deg < CAP_E ? deg : CAP_E;
    float4 ern = *(const float4*)&er[(size_t)n * 4];

    const v8h* frow8 = (const v8h*)featb;  // row = 32 chunks of 16B
    int h2 = cl >> 3;
    int dcap = deg < CAP ? deg : CAP;

    float s0 = 0.f, s1 = 0.f, s2 = 0.f, s3 = 0.f;
    v8h g0[U];
    float a0[U];
    int nbe = 0;

    if (deg <= CAP) {
        bool act = cl < deg;
        float x0 = 0.f, x1 = 0.f, x2 = 0.f, x3 = 0.f;
        if (act) {
            int s = csr[begin + cl];
            float4 e = *(const float4*)&el[(size_t)s * 4];
            float e0 = e.x + ern.x, e1 = e.y + ern.y, e2 = e.z + ern.z, e3 = e.w + ern.w;
            e0 = e0 > 0.f ? e0 : NEG_SLOPE * e0;
            e1 = e1 > 0.f ? e1 : NEG_SLOPE * e1;
            e2 = e2 > 0.f ? e2 : NEG_SLOPE * e2;
            e3 = e3 > 0.f ? e3 : NEG_SLOPE * e3;
            x0 = __expf(e0); x1 = __expf(e1);
            x2 = __expf(e2); x3 = __expf(e3);
            s_src[hw][cl] = s;
            s_alpha[hw][0][cl] = x0;
            s_alpha[hw][1][cl] = x1;
            s_alpha[hw][2][cl] = x2;
            s_alpha[hw][3][cl] = x3;
        }
        // early-issue first batch: overlaps the sum shuffle-reduce below
        if (dcap > 0) {
            nbe = dcap < U ? dcap : U;  // uniform within half-wave
#pragma unroll
            for (int u = 0; u < U; ++u) {
                if (u < nbe) {
                    int s = s_src[hw][u];
                    g0[u] = frow8[(size_t)s * 32 + cl];
                    a0[u] = s_alpha[hw][h2][u];
                }
            }
        }
        s0 = x0; s1 = x1; s2 = x2; s3 = x3;
#pragma unroll
        for (int o = 16; o >= 1; o >>= 1) {
            s0 += __shfl_xor(s0, o); s1 += __shfl_xor(s1, o);
            s2 += __shfl_xor(s2, o); s3 += __shfl_xor(s3, o);
        }
    } else {
        for (int i = cl; i < deg; i += 32) {
            int s = csr[begin + i];
            float4 e = *(const float4*)&el[(size_t)s * 4];
            float e0 = e.x + ern.x, e1 = e.y + ern.y, e2 = e.z + ern.z, e3 = e.w + ern.w;
            e0 = e0 > 0.f ? e0 : NEG_SLOPE * e0;
            e1 = e1 > 0.f ? e1 : NEG_SLOPE * e1;
            e2 = e2 > 0.f ? e2 : NEG_SLOPE * e2;
            e3 = e3 > 0.f ? e3 : NEG_SLOPE * e3;
            float x0 = __expf(e0), x1 = __expf(e1), x2 = __expf(e2), x3 = __expf(e3);
            if (i < CAP) {
                s_src[hw][i] = s;
                s_alpha[hw][0][i] = x0; s_alpha[hw][1][i] = x1;
                s_alpha[hw][2][i] = x2; s_alpha[hw][3][i] = x3;
            }
            s0 += x0; s1 += x1; s2 += x2; s3 += x3;
        }
#pragma unroll
        for (int o = 16; o >= 1; o >>= 1) {
            s0 += __shfl_xor(s0, o); s1 += __shfl_xor(s1, o);
            s2 += __shfl_xor(s2, o); s3 += __shfl_xor(s3, o);
        }
    }

    float inv0 = deg > 0 ? 1.f / s0 : 0.f;
    float inv1 = deg > 0 ? 1.f / s1 : 0.f;
    float inv2 = deg > 0 ? 1.f / s2 : 0.f;
    float inv3 = deg > 0 ? 1.f / s3 : 0.f;
    float inv = h2 == 0 ? inv0 : (h2 == 1 ? inv1 : (h2 == 2 ? inv2 : inv3));

    // ---- accumulate 8 cols/lane ----
    float c[8] = {};
    int j = 0;
    if (nbe > 0) {
#pragma unroll
        for (int u = 0; u < U; ++u) {
            if (u < nbe) {
#pragma unroll
                for (int k = 0; k < 8; ++k) c[k] += a0[u] * (float)g0[u][k];
            }
        }
        j = nbe;
    }
    for (; j + U <= dcap; j += U) {
        int s[U];
        v8h gv[U];
        float a[U];
#pragma unroll
        for (int u = 0; u < U; ++u) s[u] = s_src[hw][j + u];
#pragma unroll
        for (int u = 0; u < U; ++u) gv[u] = frow8[(size_t)s[u] * 32 + cl];
#pragma unroll
        for (int u = 0; u < U; ++u) a[u] = s_alpha[hw][h2][j + u];
#pragma unroll
        for (int u = 0; u < U; ++u) {
#pragma unroll
            for (int k = 0; k < 8; ++k) c[k] += a[u] * (float)gv[u][k];
        }
    }
    for (; j < dcap; ++j) {
        int s = s_src[hw][j];
        v8h gv = frow8[(size_t)s * 32 + cl];
        float a = s_alpha[hw][h2][j];
#pragma unroll
        for (int k = 0; k < 8; ++k) c[k] += a * (float)gv[k];
    }
    // spill path deg > CAP: recompute alpha for this lane's head (no max)
    if (deg > CAP) {
        float ernh = h2 == 0 ? ern.x : (h2 == 1 ? ern.y : (h2 == 2 ? ern.z : ern.w));
        for (int i = CAP; i < deg; ++i) {
            int s = csr[begin + i];
            float eh = el[(size_t)s * 4 + h2] + ernh;
            eh = eh > 0.f ? eh : NEG_SLOPE * eh;
            float a = __expf(eh);
            v8h gv = frow8[(size_t)s * 32 + cl];
#pragma unroll
            for (int k = 0; k < 8; ++k) c[k] += a * (float)gv[k];
        }
    }
    float4 ba = *(const float4*)&bias[8 * cl];
    float4 bb = *(const float4*)&bias[8 * cl + 4];
    float o0 = c[0] * inv + ba.x;
    float o1 = c[1] * inv + ba.y;
    float o2 = c[2] * inv + ba.z;
    float o3 = c[3] * inv + ba.w;
    float o4 = c[4] * inv + bb.x;
    float o5 = c[5] * inv + bb.y;
    float o6 = c[6] * inv + bb.z;
    float o7 = c[7] * inv + bb.w;
    uint4 pk;
    pk.x = (unsigned int)f16_bits(o0) | ((unsigned int)f16_bits(o1) << 16);
    pk.y = (unsigned int)f16_bits(o2) | ((unsigned int)f16_bits(o3) << 16);
    pk.z = (unsigned int)f16_bits(o4) | ((unsigned int)f16_bits(o5) << 16);
    pk.w = (unsigned int)f16_bits(o6) | ((unsigned int)f16_bits(o7) << 16);
    ((uint4*)outh)[(size_t)n * 32 + cl] = pk;
}

// ---------------- agg for H=1, D=16 (layer 2): 4 nodes/block --------------

template <int CAP>
__global__ __launch_bounds__(256) void agg16_kernel(const unsigned short* __restrict__ featb,
                                                    const float* __restrict__ el,
                                                    const float* __restrict__ er,
                                                    const float* __restrict__ bias,
                                                    const int* __restrict__ cnt,
                                                    const int* __restrict__ csr,
                                                    float* __restrict__ out, int N) {
    __shared__ float s_alpha[4][CAP];
    __shared__ int s_src[4][CAP];
    int w = threadIdx.x >> 6;
    int lane = threadIdx.x & 63;
    int n = blockIdx.x * 4 + w;
    if (n >= N) return;
    int begin = n * CAP_E;
    int deg = cnt[n];
    deg = deg < CAP_E ? deg : CAP_E;
    float ern = er[n];

    float ssum = 0.f;
    if (deg <= 64) {
        bool act = lane < deg;
        float x = 0.f;
        if (act) {
            int s = csr[begin + lane];
            float e = el[s] + ern;
            e = e > 0.f ? e : NEG_SLOPE * e;
            x = __expf(e);
            s_src[w][lane] = s;
            s_alpha[w][lane] = x;
        }
        ssum = x;
#pragma unroll
        for (int o = 32; o >= 1; o >>= 1) ssum += __shfl_xor(ssum, o);
    } else {
        for (int i = lane; i < deg; i += 64) {
            int s = csr[begin + i];
            float e = el[s] + ern;
            e = e > 0.f ? e : NEG_SLOPE * e;
            float x = __expf(e);
            if (i < CAP) { s_src[w][i] = s; s_alpha[w][i] = x; }
            ssum += x;
        }
#pragma unroll
        for (int o = 32; o >= 1; o >>= 1) ssum += __shfl_xor(ssum, o);
    }
    float inv = deg > 0 ? 1.f / ssum : 0.f;

    int slot = lane >> 3, p = lane & 7;
    int dcap = deg < CAP ? deg : CAP;
    const half2v* frow = (const half2v*)featb;  // row = 8 half2 (16 f16)
    float ax = 0.f, ay = 0.f;
    for (int j = slot; j < dcap; j += 8) {
        int s = s_src[w][j];
        float a = s_alpha[w][j];
        half2v f = frow[(size_t)s * 8 + p];
        ax += a * (float)f[0];
        ay += a * (float)f[1];
    }
    for (int i = CAP + slot; i < deg; i += 8) {
        int s = csr[begin + i];
        float e = el[s] + ern;
        e = e > 0.f ? e : NEG_SLOPE * e;
        float x = __expf(e);
        half2v f = frow[(size_t)s * 8 + p];
        ax += x * (float)f[0];
        ay += x * (float)f[1];
    }
#pragma unroll
    for (int o = 8; o < 64; o <<= 1) {
        ax += __shfl_xor(ax, o);
        ay += __shfl_xor(ay, o);
    }
    if (lane < 8) {
        float2 o2 = make_float2(ax * inv + bias[2 * p], ay * inv + bias[2 * p + 1]);
        *(float2*)&out[(size_t)n * 16 + 2 * p] = o2;
    }
}

// ---------------- launch ----------------

extern "C" void kernel_launch(void* const* d_in, const int* in_sizes, int n_in,
                              void* d_out, int out_size, void* d_ws, size_t ws_size,
                              hipStream_t stream) {
    const float* inputs = (const float*)d_in[0];
    const float* W0 = (const float*)d_in[1];
    const float* al0 = (const float*)d_in[2];
    const float* ar0 = (const float*)d_in[3];
    const float* b0 = (const float*)d_in[4];
    const float* W1 = (const float*)d_in[5];
    const float* al1 = (const float*)d_in[6];
    const float* ar1 = (const float*)d_in[7];
    const float* b1 = (const float*)d_in[8];
    const float* W2 = (const float*)d_in[9];
    const float* al2 = (const float*)d_in[10];
    const float* ar2 = (const float*)d_in[11];
    const float* b2 = (const float*)d_in[12];
    const int* src = (const int*)d_in[13];
    const int* dst = (const int*)d_in[14];

    const int IN_DIM = 128;
    const int N = in_sizes[0] / IN_DIM;  // 50000
    const int E = in_sizes[13];          // 800000
    float* out = (float*)d_out;

    char* base = (char*)d_ws;
    size_t o = 0;
    auto carve = [&](size_t bytes) -> void* {
        void* p = base + o;
        o += (bytes + 255) & ~(size_t)255;
        return p;
    };
    int* cnt = (int*)carve((size_t)N * sizeof(int));
    int* csr = (int*)carve((size_t)N * CAP_E * sizeof(int));
    float* el = (float*)carve((size_t)N * 4 * sizeof(float));
    float* er = (float*)carve((size_t)N * 4 * sizeof(float));
    unsigned short* featb = (unsigned short*)carve((size_t)N * 256 * sizeof(unsigned short));
    unsigned short* hbf = (unsigned short*)carve((size_t)N * 256 * sizeof(unsigned short));
    unsigned short* wt0 = (unsigned short*)carve((size_t)128 * 256 * sizeof(unsigned short));
    unsigned short* wt1 = (unsigned short*)carve((size_t)256 * 256 * sizeof(unsigned short));

    // ---- prep: zero cnt + convert W0/W1 (one dispatch) ----
    int prepTotal = N + 128 * 256 + 256 * 256;
    prep<<<(prepTotal + 255) / 256, 256, 0, stream>>>(W0, wt0, W1, wt1, cnt, N);

    int rowsP = (((N + 127) / 128) + 7) & ~7;  // pad row-blocks to x8
    // ---- fused: edge scatter + Layer-0 GEMM (fp32 A staged to f16) ----
    scatter_gemm0<<<SCAT_B + 2 * rowsP, 256, 0, stream>>>(src, dst, cnt, csr, E,
                                                          inputs, wt0, featb, el, er, al0, ar0, N);
    agg4_kernel<4><<<(N + 7) / 8, 256, 0, stream>>>(featb, el, er, b0, cnt, csr, hbf, N);

    // ---- Layer 1: 256 -> 4x64 (f16 MFMA, fused elr) ----
    {
        dim3 grid(2, rowsP);
        gemm_l1<<<grid, 256, 0, stream>>>(hbf, wt1, featb, el, er, al1, ar1, N);
        agg4_kernel<4><<<(N + 7) / 8, 256, 0, stream>>>(featb, el, er, b1, cnt, csr, hbf, N);
    }
    // ---- Layer 2: 256 -> 1x16 (MFMA, W2 hi/lo split, fused elr) ----
    {
        gemm2_mfma<<<(N + 255) / 256, 256, 0, stream>>>(hbf, W2, al2, ar2, el, er, featb, N);
        agg16_kernel<64><<<(N + 3) / 4, 256, 0, stream>>>(featb, el, er, b2, cnt, csr, out, N);
    }
}

// Round 9
// 336.714 us; speedup vs baseline: 1.0321x; 1.0321x over previous
//
#include <hip/hip_runtime.h>
#include <hip/hip_bf16.h>
#include <math.h>

// ---------------------------------------------------------------------------
// GAT 3-layer forward.
// R20: SCAT_B back to 256 (R19's 1024 regressed: atomic contention, not
// thread count, rules). Scatter loop batched 4-wide: {4 dst/src loads ->
// 4 atomicAdds in flight -> 4 csr stores} cuts serial atomic round-trips
// per thread 13 -> ~4. Everything else identical to R18 (332.7us verified).
// ---------------------------------------------------------------------------

#define NEG_SLOPE 0.2f
#define CAP_E 96
#define SCAT_B 256

typedef __attribute__((ext_vector_type(8))) _Float16 v8h;  // 8 f16 in 4 VGPRs
typedef __attribute__((ext_vector_type(2))) _Float16 half2v;
typedef __attribute__((ext_vector_type(4))) float f32x4;

// ---------------- f16 helpers ----------------

__device__ __forceinline__ unsigned short f16_bits(float x) {
    _Float16 h = (_Float16)x;
    union { _Float16 h; unsigned short u; } c;
    c.h = h;
    return c.u;
}

__device__ __forceinline__ float f16_to_f32(unsigned short u) {
    union { _Float16 h; unsigned short u; } c;
    c.u = u;
    return (float)c.h;
}

// ---------------- prep: zero cnt + convert both weight matrices -----------

__global__ __launch_bounds__(256) void prep(const float* __restrict__ W0,
                                            unsigned short* __restrict__ t0,
                                            const float* __restrict__ W1,
                                            unsigned short* __restrict__ t1,
                                            int* __restrict__ cnt, int N) {
    int idx = blockIdx.x * 256 + threadIdx.x;
    if (idx < N) cnt[idx] = 0;
    int j0 = idx - N;
    if (j0 >= 0 && j0 < 128 * 256) {
        int f = j0 >> 8, k = j0 & 255;
        t0[k * 128 + f] = f16_bits(W0[j0]);
    }
    int j1 = idx - N - 128 * 256;
    if (j1 >= 0 && j1 < 256 * 256) {
        int f = j1 >> 8, k = j1 & 255;
        t1[k * 256 + f] = f16_bits(W1[j1]);
    }
}

// ---------------- f16 MFMA GEMM body (shared by layer 0 fused + layer 1) --
// bid remap: groups of 16 bids = 8 A-rows x 2 col-blocks (A-tile L2 reuse).
// AF32: A is fp32, converted to f16 during staging (layer 0).
// Epilogue: featb repacked via LDS (Cs overlays As/Bs) -> dwordx4 stores.

template <bool AF32>
__device__ __forceinline__ void gemm_body(int bid,
                                          const unsigned short* __restrict__ Af,
                                          const float* __restrict__ A32,
                                          const unsigned short* __restrict__ Bt,
                                          unsigned short* __restrict__ featb,
                                          float* __restrict__ el,
                                          float* __restrict__ er,
                                          const float* __restrict__ al,
                                          const float* __restrict__ ar,
                                          int N, int F, int K) {
    __shared__ unsigned short smem[2 * 128 * 40];  // As + Bs; Cs overlays
    auto As = (unsigned short (*)[40])smem;
    auto Bs = (unsigned short (*)[40])(smem + 128 * 40);
    auto Cs = (unsigned short (*)[136])smem;  // 64 x 136 (17.4KB <= 20.5KB)

    int tid = threadIdx.x;
    int lane = tid & 63, w = tid >> 6;
    int wr = (w >> 1) * 64, wc = (w & 1) * 64;
    int lr = lane & 15, lq = lane >> 4;
    int g = bid >> 4, b16 = bid & 15;
    int rowb = g * 8 + (b16 & 7);
    int colb = b16 >> 3;
    int m0 = rowb * 128, n0 = colb * 128;
    if (m0 >= N) return;  // padded row-blocks: whole block exits (uniform)
    f32x4 acc[4][4] = {};

    for (int k0 = 0; k0 < F; k0 += 32) {
        __syncthreads();
#pragma unroll
        for (int i = 0; i < 2; ++i) {
            int slot = i * 256 + tid;
            int r = slot >> 2, cc = slot & 3;
            int gr = m0 + r;
            uint4 v = make_uint4(0u, 0u, 0u, 0u);
            if (AF32) {
                if (gr < N) {
                    const float* p = &A32[(size_t)gr * F + k0 + cc * 8];
                    float4 f0 = *(const float4*)p;
                    float4 f1 = *(const float4*)(p + 4);
                    v.x = (unsigned)f16_bits(f0.x) | ((unsigned)f16_bits(f0.y) << 16);
                    v.y = (unsigned)f16_bits(f0.z) | ((unsigned)f16_bits(f0.w) << 16);
                    v.z = (unsigned)f16_bits(f1.x) | ((unsigned)f16_bits(f1.y) << 16);
                    v.w = (unsigned)f16_bits(f1.z) | ((unsigned)f16_bits(f1.w) << 16);
                }
            } else {
                if (gr < N) v = *(const uint4*)&Af[(size_t)gr * F + k0 + cc * 8];
            }
            *(uint4*)&As[r][cc * 8] = v;
        }
#pragma unroll
        for (int i = 0; i < 2; ++i) {
            int slot = i * 256 + tid;
            int r = slot >> 2, cc = slot & 3;
            uint4 bv = *(const uint4*)&Bt[(size_t)(n0 + r) * F + k0 + cc * 8];
            *(uint4*)&Bs[r][cc * 8] = bv;
        }
        __syncthreads();

        v8h af[4], bf[4];
#pragma unroll
        for (int mt = 0; mt < 4; ++mt)
            af[mt] = *(const v8h*)&As[wr + mt * 16 + lr][lq * 8];
#pragma unroll
        for (int nt = 0; nt < 4; ++nt)
            bf[nt] = *(const v8h*)&Bs[wc + nt * 16 + lr][lq * 8];
#pragma unroll
        for (int mt = 0; mt < 4; ++mt)
#pragma unroll
            for (int nt = 0; nt < 4; ++nt)
                acc[mt][nt] = __builtin_amdgcn_mfma_f32_16x16x32_f16(af[mt], bf[nt], acc[mt][nt], 0, 0, 0);
    }

    // ---- el/er epilogue (registers only) ----
    int h = (n0 + wc) >> 6;
    float alw[4], arw[4];
#pragma unroll
    for (int nt = 0; nt < 4; ++nt) {
        int d = nt * 16 + lr;
        alw[nt] = al[h * 64 + d];
        arw[nt] = ar[h * 64 + d];
    }
#pragma unroll
    for (int mt = 0; mt < 4; ++mt) {
#pragma unroll
        for (int r = 0; r < 4; ++r) {
            float se = 0.f, sr = 0.f;
#pragma unroll
            for (int nt = 0; nt < 4; ++nt) {
                float v = acc[mt][nt][r];
                se += v * alw[nt];
                sr += v * arw[nt];
            }
#pragma unroll
            for (int o = 8; o >= 1; o >>= 1) {
                se += __shfl_xor(se, o);
                sr += __shfl_xor(sr, o);
            }
            int row = m0 + wr + mt * 16 + lq * 4 + r;
            if (lr == 0 && row < N) {
                el[(size_t)row * 4 + h] = se;
                er[(size_t)row * 4 + h] = sr;
            }
        }
    }

    // ---- featb epilogue via LDS repack: 2 halves of 64 rows ----
#pragma unroll
    for (int half = 0; half < 2; ++half) {
        __syncthreads();
#pragma unroll
        for (int mtl = 0; mtl < 2; ++mtl) {
            int mt = half * 2 + mtl;
            int cr = (wr >> 1) + mtl * 16 + lq * 4;
#pragma unroll
            for (int nt = 0; nt < 4; ++nt) {
                int col = wc + nt * 16 + lr;
#pragma unroll
                for (int r = 0; r < 4; ++r)
                    Cs[cr + r][col] = f16_bits(acc[mt][nt][r]);
            }
        }
        __syncthreads();
        int cr = tid >> 2, seg = (tid & 3) * 32;
        int grow = m0 + (cr & 31) + ((cr >> 5) << 6) + half * 32;
        if (grow < N) {
            uint4* dst4 = (uint4*)&featb[(size_t)grow * K + n0 + seg];
            const uint4* src4 = (const uint4*)&Cs[cr][seg];
            dst4[0] = src4[0];
            dst4[1] = src4[1];
            dst4[2] = src4[2];
            dst4[3] = src4[3];
        }
    }
}

// ---------------- fused: edge scatter (blocks 0..SCAT_B-1) + layer-0 GEMM -
// Scatter batched 4-wide: 4 loads -> 4 atomics in flight -> 4 stores.

__global__ __launch_bounds__(256) void scatter_gemm0(const int* __restrict__ src,
                                                     const int* __restrict__ dst,
                                                     int* __restrict__ cnt,
                                                     int* __restrict__ csr, int E,
                                                     const float* __restrict__ A32,
                                                     const unsigned short* __restrict__ Bt,
                                                     unsigned short* __restrict__ featb,
                                                     float* __restrict__ el,
                                                     float* __restrict__ er,
                                                     const float* __restrict__ al,
                                                     const float* __restrict__ ar,
                                                     int N) {
    if (blockIdx.x < SCAT_B) {
        const int stride = SCAT_B * 256;
        int base = blockIdx.x * 256 + threadIdx.x;
        for (int e = base; e < E; e += 4 * stride) {
            int ee[4], d[4], s[4], p[4];
            bool v[4];
#pragma unroll
            for (int u = 0; u < 4; ++u) {
                ee[u] = e + u * stride;
                v[u] = ee[u] < E;
            }
#pragma unroll
            for (int u = 0; u < 4; ++u)
                if (v[u]) { d[u] = dst[ee[u]]; s[u] = src[ee[u]]; }
#pragma unroll
            for (int u = 0; u < 4; ++u)
                if (v[u]) p[u] = atomicAdd(&cnt[d[u]], 1);
#pragma unroll
            for (int u = 0; u < 4; ++u)
                if (v[u] && p[u] < CAP_E) csr[d[u] * CAP_E + p[u]] = s[u];
        }
    } else {
        gemm_body<true>(blockIdx.x - SCAT_B, nullptr, A32, Bt, featb, el, er, al, ar, N, 128, 256);
    }
}

// ---------------- layer-1 GEMM ----------------

__global__ __launch_bounds__(256) void gemm_l1(const unsigned short* __restrict__ Af,
                                               const unsigned short* __restrict__ Bt,
                                               unsigned short* __restrict__ featb,
                                               float* __restrict__ el,
                                               float* __restrict__ er,
                                               const float* __restrict__ al,
                                               const float* __restrict__ ar,
                                               int N) {
    int bid = blockIdx.x + blockIdx.y * 2;
    gemm_body<false>(bid, Af, nullptr, Bt, featb, el, er, al, ar, N, 256, 256);
}

// ---------------- layer-2 GEMM via MFMA (K=16 out), W2 hi/lo split --------

__global__ __launch_bounds__(256) void gemm2_mfma(const unsigned short* __restrict__ Af,
                                                  const float* __restrict__ W,
                                                  const float* __restrict__ al2,
                                                  const float* __restrict__ ar2,
                                                  float* __restrict__ el,
                                                  float* __restrict__ er,
                                                  unsigned short* __restrict__ featb,
                                                  int N) {
    int tid = threadIdx.x;
    int wv = tid >> 6, lane = tid & 63;
    int lr = lane & 15, lq = lane >> 4;
    int m0 = blockIdx.x * 256 + wv * 64;
    if (m0 >= N) return;

    v8h bh[8], bl[8];
#pragma unroll
    for (int kk = 0; kk < 8; ++kk) {
#pragma unroll
        for (int j = 0; j < 8; ++j) {
            float wval = W[(kk * 32 + lq * 8 + j) * 16 + lr];
            _Float16 hi = (_Float16)wval;
            _Float16 lo = (_Float16)(wval - (float)hi);
            bh[kk][j] = hi;
            bl[kk][j] = lo;
        }
    }

    f32x4 acc[4] = {};
#pragma unroll
    for (int kk = 0; kk < 8; ++kk) {
        v8h af[4];
#pragma unroll
        for (int mt = 0; mt < 4; ++mt) {
            int row = m0 + mt * 16 + lr;
            v8h a = {};
            if (row < N) a = *(const v8h*)&Af[(size_t)row * 256 + kk * 32 + lq * 8];
            af[mt] = a;
        }
#pragma unroll
        for (int mt = 0; mt < 4; ++mt) {
            acc[mt] = __builtin_amdgcn_mfma_f32_16x16x32_f16(af[mt], bh[kk], acc[mt], 0, 0, 0);
            acc[mt] = __builtin_amdgcn_mfma_f32_16x16x32_f16(af[mt], bl[kk], acc[mt], 0, 0, 0);
        }
    }

    float alv = al2[lr], arv = ar2[lr];
#pragma unroll
    for (int mt = 0; mt < 4; ++mt) {
#pragma unroll
        for (int r = 0; r < 4; ++r) {
            int row = m0 + mt * 16 + lq * 4 + r;
            float v = acc[mt][r];
            float pe = v * alv, pr = v * arv;
            pe += __shfl_xor(pe, 1); pr += __shfl_xor(pr, 1);
            pe += __shfl_xor(pe, 2); pr += __shfl_xor(pr, 2);
            pe += __shfl_xor(pe, 4); pr += __shfl_xor(pr, 4);
            pe += __shfl_xor(pe, 8); pr += __shfl_xor(pr, 8);
            if (row < N) {
                if (lr == 0) { el[row] = pe; er[row] = pr; }
                featb[(size_t)row * 16 + lr] = f16_bits(v);
            }
        }
    }
}

// ---------------- agg for H=4, D=64: half-wave per node (R14 shape) -------

template <int U>
__global__ __launch_bounds__(256) void agg4_kernel(const unsigned short* __restrict__ featb,
                                                   const float* __restrict__ el,
                                                   const float* __restrict__ er,
                                                   const float* __restrict__ bias,
                                                   const int* __restrict__ cnt,
                                                   const int* __restrict__ csr,
                                                   unsigned short* __restrict__ outh, int N) {
    constexpr int CAP = 32;
    __shared__ float s_alpha[8][4][33];  // [halfwave][head][edge], 33-pad
    __shared__ int s_src[8][CAP];
    int hw = threadIdx.x >> 5;
    int cl = threadIdx.x & 31;
    int n = blockIdx.x * 8 + hw;
    if (n >= N) return;
    int begin = n * CAP_E;
    int deg = cnt[n];
    deg = deg < CAP_E ? deg : CAP_E;
    float4 ern = *(const float4*)&er[(size_t)n * 4];

    const v8h* frow8 = (const v8h*)featb;  // row = 32 chunks of 16B
    int h2 = cl >> 3;
    int dcap = deg < CAP ? deg : CAP;

    float s0 = 0.f, s1 = 0.f, s2 = 0.f, s3 = 0.f;
    v8h g0[U];
    float a0[U];
    int nbe = 0;

    if (deg <= CAP) {
        bool act = cl < deg;
        float x0 = 0.f, x1 = 0.f, x2 = 0.f, x3 = 0.f;
        if (act) {
            int s = csr[begin + cl];
            float4 e = *(const float4*)&el[(size_t)s * 4];
            float e0 = e.x + ern.x, e1 = e.y + ern.y, e2 = e.z + ern.z, e3 = e.w + ern.w;
            e0 = e0 > 0.f ? e0 : NEG_SLOPE * e0;
            e1 = e1 > 0.f ? e1 : NEG_SLOPE * e1;
            e2 = e2 > 0.f ? e2 : NEG_SLOPE * e2;
            e3 = e3 > 0.f ? e3 : NEG_SLOPE * e3;
            x0 = __expf(e0); x1 = __expf(e1);
            x2 = __expf(e2); x3 = __expf(e3);
            s_src[hw][cl] = s;
            s_alpha[hw][0][cl] = x0;
            s_alpha[hw][1][cl] = x1;
            s_alpha[hw][2][cl] = x2;
            s_alpha[hw][3][cl] = x3;
        }
        // early-issue first batch: overlaps the sum shuffle-reduce below
        if (dcap > 0) {
            nbe = dcap < U ? dcap : U;  // uniform within half-wave
#pragma unroll
            for (int u = 0; u < U; ++u) {
                if (u < nbe) {
                    int s = s_src[hw][u];
                    g0[u] = frow8[(size_t)s * 32 + cl];
                    a0[u] = s_alpha[hw][h2][u];
                }
            }
        }
        s0 = x0; s1 = x1; s2 = x2; s3 = x3;
#pragma unroll
        for (int o = 16; o >= 1; o >>= 1) {
            s0 += __shfl_xor(s0, o); s1 += __shfl_xor(s1, o);
            s2 += __shfl_xor(s2, o); s3 += __shfl_xor(s3, o);
        }
    } else {
        for (int i = cl; i < deg; i += 32) {
            int s = csr[begin + i];
            float4 e = *(const float4*)&el[(size_t)s * 4];
            float e0 = e.x + ern.x, e1 = e.y + ern.y, e2 = e.z + ern.z, e3 = e.w + ern.w;
            e0 = e0 > 0.f ? e0 : NEG_SLOPE * e0;
            e1 = e1 > 0.f ? e1 : NEG_SLOPE * e1;
            e2 = e2 > 0.f ? e2 : NEG_SLOPE * e2;
            e3 = e3 > 0.f ? e3 : NEG_SLOPE * e3;
            float x0 = __expf(e0), x1 = __expf(e1), x2 = __expf(e2), x3 = __expf(e3);
            if (i < CAP) {
                s_src[hw][i] = s;
                s_alpha[hw][0][i] = x0; s_alpha[hw][1][i] = x1;
                s_alpha[hw][2][i] = x2; s_alpha[hw][3][i] = x3;
            }
            s0 += x0; s1 += x1; s2 += x2; s3 += x3;
        }
#pragma unroll
        for (int o = 16; o >= 1; o >>= 1) {
            s0 += __shfl_xor(s0, o); s1 += __shfl_xor(s1, o);
            s2 += __shfl_xor(s2, o); s3 += __shfl_xor(s3, o);
        }
    }

    float inv0 = deg > 0 ? 1.f / s0 : 0.f;
    float inv1 = deg > 0 ? 1.f / s1 : 0.f;
    float inv2 = deg > 0 ? 1.f / s2 : 0.f;
    float inv3 = deg > 0 ? 1.f / s3 : 0.f;
    float inv = h2 == 0 ? inv0 : (h2 == 1 ? inv1 : (h2 == 2 ? inv2 : inv3));

    // ---- accumulate 8 cols/lane ----
    float c[8] = {};
    int j = 0;
    if (nbe > 0) {
#pragma unroll
        for (int u = 0; u < U; ++u) {
            if (u < nbe) {
#pragma unroll
                for (int k = 0; k < 8; ++k) c[k] += a0[u] * (float)g0[u][k];
            }
        }
        j = nbe;
    }
    for (; j + U <= dcap; j += U) {
        int s[U];
        v8h gv[U];
        float a[U];
#pragma unroll
        for (int u = 0; u < U; ++u) s[u] = s_src[hw][j + u];
#pragma unroll
        for (int u = 0; u < U; ++u) gv[u] = frow8[(size_t)s[u] * 32 + cl];
#pragma unroll
        for (int u = 0; u < U; ++u) a[u] = s_alpha[hw][h2][j + u];
#pragma unroll
        for (int u = 0; u < U; ++u) {
#pragma unroll
            for (int k = 0; k < 8; ++k) c[k] += a[u] * (float)gv[u][k];
        }
    }
    for (; j < dcap; ++j) {
        int s = s_src[hw][j];
        v8h gv = frow8[(size_t)s * 32 + cl];
        float a = s_alpha[hw][h2][j];
#pragma unroll
        for (int k = 0; k < 8; ++k) c[k] += a * (float)gv[k];
    }
    // spill path deg > CAP: recompute alpha for this lane's head (no max)
    if (deg > CAP) {
        float ernh = h2 == 0 ? ern.x : (h2 == 1 ? ern.y : (h2 == 2 ? ern.z : ern.w));
        for (int i = CAP; i < deg; ++i) {
            int s = csr[begin + i];
            float eh = el[(size_t)s * 4 + h2] + ernh;
            eh = eh > 0.f ? eh : NEG_SLOPE * eh;
            float a = __expf(eh);
            v8h gv = frow8[(size_t)s * 32 + cl];
#pragma unroll
            for (int k = 0; k < 8; ++k) c[k] += a * (float)gv[k];
        }
    }
    float4 ba = *(const float4*)&bias[8 * cl];
    float4 bb = *(const float4*)&bias[8 * cl + 4];
    float o0 = c[0] * inv + ba.x;
    float o1 = c[1] * inv + ba.y;
    float o2 = c[2] * inv + ba.z;
    float o3 = c[3] * inv + ba.w;
    float o4 = c[4] * inv + bb.x;
    float o5 = c[5] * inv + bb.y;
    float o6 = c[6] * inv + bb.z;
    float o7 = c[7] * inv + bb.w;
    uint4 pk;
    pk.x = (unsigned int)f16_bits(o0) | ((unsigned int)f16_bits(o1) << 16);
    pk.y = (unsigned int)f16_bits(o2) | ((unsigned int)f16_bits(o3) << 16);
    pk.z = (unsigned int)f16_bits(o4) | ((unsigned int)f16_bits(o5) << 16);
    pk.w = (unsigned int)f16_bits(o6) | ((unsigned int)f16_bits(o7) << 16);
    ((uint4*)outh)[(size_t)n * 32 + cl] = pk;
}

// ---------------- agg for H=1, D=16 (layer 2): 4 nodes/block --------------

template <int CAP>
__global__ __launch_bounds__(256) void agg16_kernel(const unsigned short* __restrict__ featb,
                                                    const float* __restrict__ el,
                                                    const float* __restrict__ er,
                                                    const float* __restrict__ bias,
                                                    const int* __restrict__ cnt,
                                                    const int* __restrict__ csr,
                                                    float* __restrict__ out, int N) {
    __shared__ float s_alpha[4][CAP];
    __shared__ int s_src[4][CAP];
    int w = threadIdx.x >> 6;
    int lane = threadIdx.x & 63;
    int n = blockIdx.x * 4 + w;
    if (n >= N) return;
    int begin = n * CAP_E;
    int deg = cnt[n];
    deg = deg < CAP_E ? deg : CAP_E;
    float ern = er[n];

    float ssum = 0.f;
    if (deg <= 64) {
        bool act = lane < deg;
        float x = 0.f;
        if (act) {
            int s = csr[begin + lane];
            float e = el[s] + ern;
            e = e > 0.f ? e : NEG_SLOPE * e;
            x = __expf(e);
            s_src[w][lane] = s;
            s_alpha[w][lane] = x;
        }
        ssum = x;
#pragma unroll
        for (int o = 32; o >= 1; o >>= 1) ssum += __shfl_xor(ssum, o);
    } else {
        for (int i = lane; i < deg; i += 64) {
            int s = csr[begin + i];
            float e = el[s] + ern;
            e = e > 0.f ? e : NEG_SLOPE * e;
            float x = __expf(e);
            if (i < CAP) { s_src[w][i] = s; s_alpha[w][i] = x; }
            ssum += x;
        }
#pragma unroll
        for (int o = 32; o >= 1; o >>= 1) ssum += __shfl_xor(ssum, o);
    }
    float inv = deg > 0 ? 1.f / ssum : 0.f;

    int slot = lane >> 3, p = lane & 7;
    int dcap = deg < CAP ? deg : CAP;
    const half2v* frow = (const half2v*)featb;  // row = 8 half2 (16 f16)
    float ax = 0.f, ay = 0.f;
    for (int j = slot; j < dcap; j += 8) {
        int s = s_src[w][j];
        float a = s_alpha[w][j];
        half2v f = frow[(size_t)s * 8 + p];
        ax += a * (float)f[0];
        ay += a * (float)f[1];
    }
    for (int i = CAP + slot; i < deg; i += 8) {
        int s = csr[begin + i];
        float e = el[s] + ern;
        e = e > 0.f ? e : NEG_SLOPE * e;
        float x = __expf(e);
        half2v f = frow[(size_t)s * 8 + p];
        ax += x * (float)f[0];
        ay += x * (float)f[1];
    }
#pragma unroll
    for (int o = 8; o < 64; o <<= 1) {
        ax += __shfl_xor(ax, o);
        ay += __shfl_xor(ay, o);
    }
    if (lane < 8) {
        float2 o2 = make_float2(ax * inv + bias[2 * p], ay * inv + bias[2 * p + 1]);
        *(float2*)&out[(size_t)n * 16 + 2 * p] = o2;
    }
}

// ---------------- launch ----------------

extern "C" void kernel_launch(void* const* d_in, const int* in_sizes, int n_in,
                              void* d_out, int out_size, void* d_ws, size_t ws_size,
                              hipStream_t stream) {
    const float* inputs = (const float*)d_in[0];
    const float* W0 = (const float*)d_in[1];
    const float* al0 = (const float*)d_in[2];
    const float* ar0 = (const float*)d_in[3];
    const float* b0 = (const float*)d_in[4];
    const float* W1 = (const float*)d_in[5];
    const float* al1 = (const float*)d_in[6];
    const float* ar1 = (const float*)d_in[7];
    const float* b1 = (const float*)d_in[8];
    const float* W2 = (const float*)d_in[9];
    const float* al2 = (const float*)d_in[10];
    const float* ar2 = (const float*)d_in[11];
    const float* b2 = (const float*)d_in[12];
    const int* src = (const int*)d_in[13];
    const int* dst = (const int*)d_in[14];

    const int IN_DIM = 128;
    const int N = in_sizes[0] / IN_DIM;  // 50000
    const int E = in_sizes[13];          // 800000
    float* out = (float*)d_out;

    char* base = (char*)d_ws;
    size_t o = 0;
    auto carve = [&](size_t bytes) -> void* {
        void* p = base + o;
        o += (bytes + 255) & ~(size_t)255;
        return p;
    };
    int* cnt = (int*)carve((size_t)N * sizeof(int));
    int* csr = (int*)carve((size_t)N * CAP_E * sizeof(int));
    float* el = (float*)carve((size_t)N * 4 * sizeof(float));
    float* er = (float*)carve((size_t)N * 4 * sizeof(float));
    unsigned short* featb = (unsigned short*)carve((size_t)N * 256 * sizeof(unsigned short));
    unsigned short* hbf = (unsigned short*)carve((size_t)N * 256 * sizeof(unsigned short));
    unsigned short* wt0 = (unsigned short*)carve((size_t)128 * 256 * sizeof(unsigned short));
    unsigned short* wt1 = (unsigned short*)carve((size_t)256 * 256 * sizeof(unsigned short));

    // ---- prep: zero cnt + convert W0/W1 (one dispatch) ----
    int prepTotal = N + 128 * 256 + 256 * 256;
    prep<<<(prepTotal + 255) / 256, 256, 0, stream>>>(W0, wt0, W1, wt1, cnt, N);

    int rowsP = (((N + 127) / 128) + 7) & ~7;  // pad row-blocks to x8
    // ---- fused: edge scatter + Layer-0 GEMM (fp32 A staged to f16) ----
    scatter_gemm0<<<SCAT_B + 2 * rowsP, 256, 0, stream>>>(src, dst, cnt, csr, E,
                                                          inputs, wt0, featb, el, er, al0, ar0, N);
    agg4_kernel<4><<<(N + 7) / 8, 256, 0, stream>>>(featb, el, er, b0, cnt, csr, hbf, N);

    // ---- Layer 1: 256 -> 4x64 (f16 MFMA, fused elr) ----
    {
        dim3 grid(2, rowsP);
        gemm_l1<<<grid, 256, 0, stream>>>(hbf, wt1, featb, el, er, al1, ar1, N);
        agg4_kernel<4><<<(N + 7) / 8, 256, 0, stream>>>(featb, el, er, b1, cnt, csr, hbf, N);
    }
    // ---- Layer 2: 256 -> 1x16 (MFMA, W2 hi/lo split, fused elr) ----
    {
        gemm2_mfma<<<(N + 255) / 256, 256, 0, stream>>>(hbf, W2, al2, ar2, el, er, featb, N);
        agg16_kernel<64><<<(N + 3) / 4, 256, 0, stream>>>(featb, el, er, b2, cnt, csr, out, N);
    }
}

// Round 10
// 333.076 us; speedup vs baseline: 1.0433x; 1.0109x over previous
//
#include <hip/hip_runtime.h>
#include <hip/hip_bf16.h>
#include <math.h>

// ---------------------------------------------------------------------------
// GAT 3-layer forward.
// R21 = R18-exact revert (best measured: 332.7us). R19 (1024 scatter blocks)
// and R20 (4-wide atomic batching) both REGRESSED the fused scatter ->
// scatter is device-atomic/random-write throughput-bound; R18's 256-block
// serial loop paces it best. agg4 at random-512B-gather floor (R12-R15);
// scatter at atomic/write floor (R18-R20). This is the practical floor
// pending a structurally different algorithm.
// ---------------------------------------------------------------------------

#define NEG_SLOPE 0.2f
#define CAP_E 96
#define SCAT_B 256

typedef __attribute__((ext_vector_type(8))) _Float16 v8h;  // 8 f16 in 4 VGPRs
typedef __attribute__((ext_vector_type(2))) _Float16 half2v;
typedef __attribute__((ext_vector_type(4))) float f32x4;

// ---------------- f16 helpers ----------------

__device__ __forceinline__ unsigned short f16_bits(float x) {
    _Float16 h = (_Float16)x;
    union { _Float16 h; unsigned short u; } c;
    c.h = h;
    return c.u;
}

__device__ __forceinline__ float f16_to_f32(unsigned short u) {
    union { _Float16 h; unsigned short u; } c;
    c.u = u;
    return (float)c.h;
}

// ---------------- prep: zero cnt + convert both weight matrices -----------

__global__ __launch_bounds__(256) void prep(const float* __restrict__ W0,
                                            unsigned short* __restrict__ t0,
                                            const float* __restrict__ W1,
                                            unsigned short* __restrict__ t1,
                                            int* __restrict__ cnt, int N) {
    int idx = blockIdx.x * 256 + threadIdx.x;
    if (idx < N) cnt[idx] = 0;
    int j0 = idx - N;
    if (j0 >= 0 && j0 < 128 * 256) {
        int f = j0 >> 8, k = j0 & 255;
        t0[k * 128 + f] = f16_bits(W0[j0]);
    }
    int j1 = idx - N - 128 * 256;
    if (j1 >= 0 && j1 < 256 * 256) {
        int f = j1 >> 8, k = j1 & 255;
        t1[k * 256 + f] = f16_bits(W1[j1]);
    }
}

// ---------------- f16 MFMA GEMM body (shared by layer 0 fused + layer 1) --
// bid remap: groups of 16 bids = 8 A-rows x 2 col-blocks (A-tile L2 reuse).
// AF32: A is fp32, converted to f16 during staging (layer 0).
// Epilogue: featb repacked via LDS (Cs overlays As/Bs) -> dwordx4 stores.

template <bool AF32>
__device__ __forceinline__ void gemm_body(int bid,
                                          const unsigned short* __restrict__ Af,
                                          const float* __restrict__ A32,
                                          const unsigned short* __restrict__ Bt,
                                          unsigned short* __restrict__ featb,
                                          float* __restrict__ el,
                                          float* __restrict__ er,
                                          const float* __restrict__ al,
                                          const float* __restrict__ ar,
                                          int N, int F, int K) {
    __shared__ unsigned short smem[2 * 128 * 40];  // As + Bs; Cs overlays
    auto As = (unsigned short (*)[40])smem;
    auto Bs = (unsigned short (*)[40])(smem + 128 * 40);
    auto Cs = (unsigned short (*)[136])smem;  // 64 x 136 (17.4KB <= 20.5KB)

    int tid = threadIdx.x;
    int lane = tid & 63, w = tid >> 6;
    int wr = (w >> 1) * 64, wc = (w & 1) * 64;
    int lr = lane & 15, lq = lane >> 4;
    int g = bid >> 4, b16 = bid & 15;
    int rowb = g * 8 + (b16 & 7);
    int colb = b16 >> 3;
    int m0 = rowb * 128, n0 = colb * 128;
    if (m0 >= N) return;  // padded row-blocks: whole block exits (uniform)
    f32x4 acc[4][4] = {};

    for (int k0 = 0; k0 < F; k0 += 32) {
        __syncthreads();
#pragma unroll
        for (int i = 0; i < 2; ++i) {
            int slot = i * 256 + tid;
            int r = slot >> 2, cc = slot & 3;
            int gr = m0 + r;
            uint4 v = make_uint4(0u, 0u, 0u, 0u);
            if (AF32) {
                if (gr < N) {
                    const float* p = &A32[(size_t)gr * F + k0 + cc * 8];
                    float4 f0 = *(const float4*)p;
                    float4 f1 = *(const float4*)(p + 4);
                    v.x = (unsigned)f16_bits(f0.x) | ((unsigned)f16_bits(f0.y) << 16);
                    v.y = (unsigned)f16_bits(f0.z) | ((unsigned)f16_bits(f0.w) << 16);
                    v.z = (unsigned)f16_bits(f1.x) | ((unsigned)f16_bits(f1.y) << 16);
                    v.w = (unsigned)f16_bits(f1.z) | ((unsigned)f16_bits(f1.w) << 16);
                }
            } else {
                if (gr < N) v = *(const uint4*)&Af[(size_t)gr * F + k0 + cc * 8];
            }
            *(uint4*)&As[r][cc * 8] = v;
        }
#pragma unroll
        for (int i = 0; i < 2; ++i) {
            int slot = i * 256 + tid;
            int r = slot >> 2, cc = slot & 3;
            uint4 bv = *(const uint4*)&Bt[(size_t)(n0 + r) * F + k0 + cc * 8];
            *(uint4*)&Bs[r][cc * 8] = bv;
        }
        __syncthreads();

        v8h af[4], bf[4];
#pragma unroll
        for (int mt = 0; mt < 4; ++mt)
            af[mt] = *(const v8h*)&As[wr + mt * 16 + lr][lq * 8];
#pragma unroll
        for (int nt = 0; nt < 4; ++nt)
            bf[nt] = *(const v8h*)&Bs[wc + nt * 16 + lr][lq * 8];
#pragma unroll
        for (int mt = 0; mt < 4; ++mt)
#pragma unroll
            for (int nt = 0; nt < 4; ++nt)
                acc[mt][nt] = __builtin_amdgcn_mfma_f32_16x16x32_f16(af[mt], bf[nt], acc[mt][nt], 0, 0, 0);
    }

    // ---- el/er epilogue (registers only) ----
    int h = (n0 + wc) >> 6;
    float alw[4], arw[4];
#pragma unroll
    for (int nt = 0; nt < 4; ++nt) {
        int d = nt * 16 + lr;
        alw[nt] = al[h * 64 + d];
        arw[nt] = ar[h * 64 + d];
    }
#pragma unroll
    for (int mt = 0; mt < 4; ++mt) {
#pragma unroll
        for (int r = 0; r < 4; ++r) {
            float se = 0.f, sr = 0.f;
#pragma unroll
            for (int nt = 0; nt < 4; ++nt) {
                float v = acc[mt][nt][r];
                se += v * alw[nt];
                sr += v * arw[nt];
            }
#pragma unroll
            for (int o = 8; o >= 1; o >>= 1) {
                se += __shfl_xor(se, o);
                sr += __shfl_xor(sr, o);
            }
            int row = m0 + wr + mt * 16 + lq * 4 + r;
            if (lr == 0 && row < N) {
                el[(size_t)row * 4 + h] = se;
                er[(size_t)row * 4 + h] = sr;
            }
        }
    }

    // ---- featb epilogue via LDS repack: 2 halves of 64 rows ----
#pragma unroll
    for (int half = 0; half < 2; ++half) {
        __syncthreads();
#pragma unroll
        for (int mtl = 0; mtl < 2; ++mtl) {
            int mt = half * 2 + mtl;
            int cr = (wr >> 1) + mtl * 16 + lq * 4;
#pragma unroll
            for (int nt = 0; nt < 4; ++nt) {
                int col = wc + nt * 16 + lr;
#pragma unroll
                for (int r = 0; r < 4; ++r)
                    Cs[cr + r][col] = f16_bits(acc[mt][nt][r]);
            }
        }
        __syncthreads();
        int cr = tid >> 2, seg = (tid & 3) * 32;
        int grow = m0 + (cr & 31) + ((cr >> 5) << 6) + half * 32;
        if (grow < N) {
            uint4* dst4 = (uint4*)&featb[(size_t)grow * K + n0 + seg];
            const uint4* src4 = (const uint4*)&Cs[cr][seg];
            dst4[0] = src4[0];
            dst4[1] = src4[1];
            dst4[2] = src4[2];
            dst4[3] = src4[3];
        }
    }
}

// ---------------- fused: edge scatter (blocks 0..SCAT_B-1) + layer-0 GEMM -
// Serial scatter loop (R18 form): measured-fastest pacing for the
// device-atomic stream; wider/batched variants regressed (R19/R20).

__global__ __launch_bounds__(256) void scatter_gemm0(const int* __restrict__ src,
                                                     const int* __restrict__ dst,
                                                     int* __restrict__ cnt,
                                                     int* __restrict__ csr, int E,
                                                     const float* __restrict__ A32,
                                                     const unsigned short* __restrict__ Bt,
                                                     unsigned short* __restrict__ featb,
                                                     float* __restrict__ el,
                                                     float* __restrict__ er,
                                                     const float* __restrict__ al,
                                                     const float* __restrict__ ar,
                                                     int N) {
    if (blockIdx.x < SCAT_B) {
        int stride = SCAT_B * 256;
        for (int e = blockIdx.x * 256 + threadIdx.x; e < E; e += stride) {
            int d = dst[e];
            int pos = atomicAdd(&cnt[d], 1);
            if (pos < CAP_E) csr[d * CAP_E + pos] = src[e];
        }
    } else {
        gemm_body<true>(blockIdx.x - SCAT_B, nullptr, A32, Bt, featb, el, er, al, ar, N, 128, 256);
    }
}

// ---------------- layer-1 GEMM ----------------

__global__ __launch_bounds__(256) void gemm_l1(const unsigned short* __restrict__ Af,
                                               const unsigned short* __restrict__ Bt,
                                               unsigned short* __restrict__ featb,
                                               float* __restrict__ el,
                                               float* __restrict__ er,
                                               const float* __restrict__ al,
                                               const float* __restrict__ ar,
                                               int N) {
    int bid = blockIdx.x + blockIdx.y * 2;
    gemm_body<false>(bid, Af, nullptr, Bt, featb, el, er, al, ar, N, 256, 256);
}

// ---------------- layer-2 GEMM via MFMA (K=16 out), W2 hi/lo split --------

__global__ __launch_bounds__(256) void gemm2_mfma(const unsigned short* __restrict__ Af,
                                                  const float* __restrict__ W,
                                                  const float* __restrict__ al2,
                                                  const float* __restrict__ ar2,
                                                  float* __restrict__ el,
                                                  float* __restrict__ er,
                                                  unsigned short* __restrict__ featb,
                                                  int N) {
    int tid = threadIdx.x;
    int wv = tid >> 6, lane = tid & 63;
    int lr = lane & 15, lq = lane >> 4;
    int m0 = blockIdx.x * 256 + wv * 64;
    if (m0 >= N) return;

    v8h bh[8], bl[8];
#pragma unroll
    for (int kk = 0; kk < 8; ++kk) {
#pragma unroll
        for (int j = 0; j < 8; ++j) {
            float wval = W[(kk * 32 + lq * 8 + j) * 16 + lr];
            _Float16 hi = (_Float16)wval;
            _Float16 lo = (_Float16)(wval - (float)hi);
            bh[kk][j] = hi;
            bl[kk][j] = lo;
        }
    }

    f32x4 acc[4] = {};
#pragma unroll
    for (int kk = 0; kk < 8; ++kk) {
        v8h af[4];
#pragma unroll
        for (int mt = 0; mt < 4; ++mt) {
            int row = m0 + mt * 16 + lr;
            v8h a = {};
            if (row < N) a = *(const v8h*)&Af[(size_t)row * 256 + kk * 32 + lq * 8];
            af[mt] = a;
        }
#pragma unroll
        for (int mt = 0; mt < 4; ++mt) {
            acc[mt] = __builtin_amdgcn_mfma_f32_16x16x32_f16(af[mt], bh[kk], acc[mt], 0, 0, 0);
            acc[mt] = __builtin_amdgcn_mfma_f32_16x16x32_f16(af[mt], bl[kk], acc[mt], 0, 0, 0);
        }
    }

    float alv = al2[lr], arv = ar2[lr];
#pragma unroll
    for (int mt = 0; mt < 4; ++mt) {
#pragma unroll
        for (int r = 0; r < 4; ++r) {
            int row = m0 + mt * 16 + lq * 4 + r;
            float v = acc[mt][r];
            float pe = v * alv, pr = v * arv;
            pe += __shfl_xor(pe, 1); pr += __shfl_xor(pr, 1);
            pe += __shfl_xor(pe, 2); pr += __shfl_xor(pr, 2);
            pe += __shfl_xor(pe, 4); pr += __shfl_xor(pr, 4);
            pe += __shfl_xor(pe, 8); pr += __shfl_xor(pr, 8);
            if (row < N) {
                if (lr == 0) { el[row] = pe; er[row] = pr; }
                featb[(size_t)row * 16 + lr] = f16_bits(v);
            }
        }
    }
}

// ---------------- agg for H=4, D=64: half-wave per node (R14 shape) -------

template <int U>
__global__ __launch_bounds__(256) void agg4_kernel(const unsigned short* __restrict__ featb,
                                                   const float* __restrict__ el,
                                                   const float* __restrict__ er,
                                                   const float* __restrict__ bias,
                                                   const int* __restrict__ cnt,
                                                   const int* __restrict__ csr,
                                                   unsigned short* __restrict__ outh, int N) {
    constexpr int CAP = 32;
    __shared__ float s_alpha[8][4][33];  // [halfwave][head][edge], 33-pad
    __shared__ int s_src[8][CAP];
    int hw = threadIdx.x >> 5;
    int cl = threadIdx.x & 31;
    int n = blockIdx.x * 8 + hw;
    if (n >= N) return;
    int begin = n * CAP_E;
    int deg = cnt[n];
    deg = deg < CAP_E ? deg : CAP_E;
    float4 ern = *(const float4*)&er[(size_t)n * 4];

    const v8h* frow8 = (const v8h*)featb;  // row = 32 chunks of 16B
    int h2 = cl >> 3;
    int dcap = deg < CAP ? deg : CAP;

    float s0 = 0.f, s1 = 0.f, s2 = 0.f, s3 = 0.f;
    v8h g0[U];
    float a0[U];
    int nbe = 0;

    if (deg <= CAP) {
        bool act = cl < deg;
        float x0 = 0.f, x1 = 0.f, x2 = 0.f, x3 = 0.f;
        if (act) {
            int s = csr[begin + cl];
            float4 e = *(const float4*)&el[(size_t)s * 4];
            float e0 = e.x + ern.x, e1 = e.y + ern.y, e2 = e.z + ern.z, e3 = e.w + ern.w;
            e0 = e0 > 0.f ? e0 : NEG_SLOPE * e0;
            e1 = e1 > 0.f ? e1 : NEG_SLOPE * e1;
            e2 = e2 > 0.f ? e2 : NEG_SLOPE * e2;
            e3 = e3 > 0.f ? e3 : NEG_SLOPE * e3;
            x0 = __expf(e0); x1 = __expf(e1);
            x2 = __expf(e2); x3 = __expf(e3);
            s_src[hw][cl] = s;
            s_alpha[hw][0][cl] = x0;
            s_alpha[hw][1][cl] = x1;
            s_alpha[hw][2][cl] = x2;
            s_alpha[hw][3][cl] = x3;
        }
        // early-issue first batch: overlaps the sum shuffle-reduce below
        if (dcap > 0) {
            nbe = dcap < U ? dcap : U;  // uniform within half-wave
#pragma unroll
            for (int u = 0; u < U; ++u) {
                if (u < nbe) {
                    int s = s_src[hw][u];
                    g0[u] = frow8[(size_t)s * 32 + cl];
                    a0[u] = s_alpha[hw][h2][u];
                }
            }
        }
        s0 = x0; s1 = x1; s2 = x2; s3 = x3;
#pragma unroll
        for (int o = 16; o >= 1; o >>= 1) {
            s0 += __shfl_xor(s0, o); s1 += __shfl_xor(s1, o);
            s2 += __shfl_xor(s2, o); s3 += __shfl_xor(s3, o);
        }
    } else {
        for (int i = cl; i < deg; i += 32) {
            int s = csr[begin + i];
            float4 e = *(const float4*)&el[(size_t)s * 4];
            float e0 = e.x + ern.x, e1 = e.y + ern.y, e2 = e.z + ern.z, e3 = e.w + ern.w;
            e0 = e0 > 0.f ? e0 : NEG_SLOPE * e0;
            e1 = e1 > 0.f ? e1 : NEG_SLOPE * e1;
            e2 = e2 > 0.f ? e2 : NEG_SLOPE * e2;
            e3 = e3 > 0.f ? e3 : NEG_SLOPE * e3;
            float x0 = __expf(e0), x1 = __expf(e1), x2 = __expf(e2), x3 = __expf(e3);
            if (i < CAP) {
                s_src[hw][i] = s;
                s_alpha[hw][0][i] = x0; s_alpha[hw][1][i] = x1;
                s_alpha[hw][2][i] = x2; s_alpha[hw][3][i] = x3;
            }
            s0 += x0; s1 += x1; s2 += x2; s3 += x3;
        }
#pragma unroll
        for (int o = 16; o >= 1; o >>= 1) {
            s0 += __shfl_xor(s0, o); s1 += __shfl_xor(s1, o);
            s2 += __shfl_xor(s2, o); s3 += __shfl_xor(s3, o);
        }
    }

    float inv0 = deg > 0 ? 1.f / s0 : 0.f;
    float inv1 = deg > 0 ? 1.f / s1 : 0.f;
    float inv2 = deg > 0 ? 1.f / s2 : 0.f;
    float inv3 = deg > 0 ? 1.f / s3 : 0.f;
    float inv = h2 == 0 ? inv0 : (h2 == 1 ? inv1 : (h2 == 2 ? inv2 : inv3));

    // ---- accumulate 8 cols/lane ----
    float c[8] = {};
    int j = 0;
    if (nbe > 0) {
#pragma unroll
        for (int u = 0; u < U; ++u) {
            if (u < nbe) {
#pragma unroll
                for (int k = 0; k < 8; ++k) c[k] += a0[u] * (float)g0[u][k];
            }
        }
        j = nbe;
    }
    for (; j + U <= dcap; j += U) {
        int s[U];
        v8h gv[U];
        float a[U];
#pragma unroll
        for (int u = 0; u < U; ++u) s[u] = s_src[hw][j + u];
#pragma unroll
        for (int u = 0; u < U; ++u) gv[u] = frow8[(size_t)s[u] * 32 + cl];
#pragma unroll
        for (int u = 0; u < U; ++u) a[u] = s_alpha[hw][h2][j + u];
#pragma unroll
        for (int u = 0; u < U; ++u) {
#pragma unroll
            for (int k = 0; k < 8; ++k) c[k] += a[u] * (float)gv[u][k];
        }
    }
    for (; j < dcap; ++j) {
        int s = s_src[hw][j];
        v8h gv = frow8[(size_t)s * 32 + cl];
        float a = s_alpha[hw][h2][j];
#pragma unroll
        for (int k = 0; k < 8; ++k) c[k] += a * (float)gv[k];
    }
    // spill path deg > CAP: recompute alpha for this lane's head (no max)
    if (deg > CAP) {
        float ernh = h2 == 0 ? ern.x : (h2 == 1 ? ern.y : (h2 == 2 ? ern.z : ern.w));
        for (int i = CAP; i < deg; ++i) {
            int s = csr[begin + i];
            float eh = el[(size_t)s * 4 + h2] + ernh;
            eh = eh > 0.f ? eh : NEG_SLOPE * eh;
            float a = __expf(eh);
            v8h gv = frow8[(size_t)s * 32 + cl];
#pragma unroll
            for (int k = 0; k < 8; ++k) c[k] += a * (float)gv[k];
        }
    }
    float4 ba = *(const float4*)&bias[8 * cl];
    float4 bb = *(const float4*)&bias[8 * cl + 4];
    float o0 = c[0] * inv + ba.x;
    float o1 = c[1] * inv + ba.y;
    float o2 = c[2] * inv + ba.z;
    float o3 = c[3] * inv + ba.w;
    float o4 = c[4] * inv + bb.x;
    float o5 = c[5] * inv + bb.y;
    float o6 = c[6] * inv + bb.z;
    float o7 = c[7] * inv + bb.w;
    uint4 pk;
    pk.x = (unsigned int)f16_bits(o0) | ((unsigned int)f16_bits(o1) << 16);
    pk.y = (unsigned int)f16_bits(o2) | ((unsigned int)f16_bits(o3) << 16);
    pk.z = (unsigned int)f16_bits(o4) | ((unsigned int)f16_bits(o5) << 16);
    pk.w = (unsigned int)f16_bits(o6) | ((unsigned int)f16_bits(o7) << 16);
    ((uint4*)outh)[(size_t)n * 32 + cl] = pk;
}

// ---------------- agg for H=1, D=16 (layer 2): 4 nodes/block --------------

template <int CAP>
__global__ __launch_bounds__(256) void agg16_kernel(const unsigned short* __restrict__ featb,
                                                    const float* __restrict__ el,
                                                    const float* __restrict__ er,
                                                    const float* __restrict__ bias,
                                                    const int* __restrict__ cnt,
                                                    const int* __restrict__ csr,
                                                    float* __restrict__ out, int N) {
    __shared__ float s_alpha[4][CAP];
    __shared__ int s_src[4][CAP];
    int w = threadIdx.x >> 6;
    int lane = threadIdx.x & 63;
    int n = blockIdx.x * 4 + w;
    if (n >= N) return;
    int begin = n * CAP_E;
    int deg = cnt[n];
    deg = deg < CAP_E ? deg : CAP_E;
    float ern = er[n];

    float ssum = 0.f;
    if (deg <= 64) {
        bool act = lane < deg;
        float x = 0.f;
        if (act) {
            int s = csr[begin + lane];
            float e = el[s] + ern;
            e = e > 0.f ? e : NEG_SLOPE * e;
            x = __expf(e);
            s_src[w][lane] = s;
            s_alpha[w][lane] = x;
        }
        ssum = x;
#pragma unroll
        for (int o = 32; o >= 1; o >>= 1) ssum += __shfl_xor(ssum, o);
    } else {
        for (int i = lane; i < deg; i += 64) {
            int s = csr[begin + i];
            float e = el[s] + ern;
            e = e > 0.f ? e : NEG_SLOPE * e;
            float x = __expf(e);
            if (i < CAP) { s_src[w][i] = s; s_alpha[w][i] = x; }
            ssum += x;
        }
#pragma unroll
        for (int o = 32; o >= 1; o >>= 1) ssum += __shfl_xor(ssum, o);
    }
    float inv = deg > 0 ? 1.f / ssum : 0.f;

    int slot = lane >> 3, p = lane & 7;
    int dcap = deg < CAP ? deg : CAP;
    const half2v* frow = (const half2v*)featb;  // row = 8 half2 (16 f16)
    float ax = 0.f, ay = 0.f;
    for (int j = slot; j < dcap; j += 8) {
        int s = s_src[w][j];
        float a = s_alpha[w][j];
        half2v f = frow[(size_t)s * 8 + p];
        ax += a * (float)f[0];
        ay += a * (float)f[1];
    }
    for (int i = CAP + slot; i < deg; i += 8) {
        int s = csr[begin + i];
        float e = el[s] + ern;
        e = e > 0.f ? e : NEG_SLOPE * e;
        float x = __expf(e);
        half2v f = frow[(size_t)s * 8 + p];
        ax += x * (float)f[0];
        ay += x * (float)f[1];
    }
#pragma unroll
    for (int o = 8; o < 64; o <<= 1) {
        ax += __shfl_xor(ax, o);
        ay += __shfl_xor(ay, o);
    }
    if (lane < 8) {
        float2 o2 = make_float2(ax * inv + bias[2 * p], ay * inv + bias[2 * p + 1]);
        *(float2*)&out[(size_t)n * 16 + 2 * p] = o2;
    }
}

// ---------------- launch ----------------

extern "C" void kernel_launch(void* const* d_in, const int* in_sizes, int n_in,
                              void* d_out, int out_size, void* d_ws, size_t ws_size,
                              hipStream_t stream) {
    const float* inputs = (const float*)d_in[0];
    const float* W0 = (const float*)d_in[1];
    const float* al0 = (const float*)d_in[2];
    const float* ar0 = (const float*)d_in[3];
    const float* b0 = (const float*)d_in[4];
    const float* W1 = (const float*)d_in[5];
    const float* al1 = (const float*)d_in[6];
    const float* ar1 = (const float*)d_in[7];
    const float* b1 = (const float*)d_in[8];
    const float* W2 = (const float*)d_in[9];
    const float* al2 = (const float*)d_in[10];
    const float* ar2 = (const float*)d_in[11];
    const float* b2 = (const float*)d_in[12];
    const int* src = (const int*)d_in[13];
    const int* dst = (const int*)d_in[14];

    const int IN_DIM = 128;
    const int N = in_sizes[0] / IN_DIM;  // 50000
    const int E = in_sizes[13];          // 800000
    float* out = (float*)d_out;

    char* base = (char*)d_ws;
    size_t o = 0;
    auto carve = [&](size_t bytes) -> void* {
        void* p = base + o;
        o += (bytes + 255) & ~(size_t)255;
        return p;
    };
    int* cnt = (int*)carve((size_t)N * sizeof(int));
    int* csr = (int*)carve((size_t)N * CAP_E * sizeof(int));
    float* el = (float*)carve((size_t)N * 4 * sizeof(float));
    float* er = (float*)carve((size_t)N * 4 * sizeof(float));
    unsigned short* featb = (unsigned short*)carve((size_t)N * 256 * sizeof(unsigned short));
    unsigned short* hbf = (unsigned short*)carve((size_t)N * 256 * sizeof(unsigned short));
    unsigned short* wt0 = (unsigned short*)carve((size_t)128 * 256 * sizeof(unsigned short));
    unsigned short* wt1 = (unsigned short*)carve((size_t)256 * 256 * sizeof(unsigned short));

    // ---- prep: zero cnt + convert W0/W1 (one dispatch) ----
    int prepTotal = N + 128 * 256 + 256 * 256;
    prep<<<(prepTotal + 255) / 256, 256, 0, stream>>>(W0, wt0, W1, wt1, cnt, N);

    int rowsP = (((N + 127) / 128) + 7) & ~7;  // pad row-blocks to x8
    // ---- fused: edge scatter + Layer-0 GEMM (fp32 A staged to f16) ----
    scatter_gemm0<<<SCAT_B + 2 * rowsP, 256, 0, stream>>>(src, dst, cnt, csr, E,
                                                          inputs, wt0, featb, el, er, al0, ar0, N);
    agg4_kernel<4><<<(N + 7) / 8, 256, 0, stream>>>(featb, el, er, b0, cnt, csr, hbf, N);

    // ---- Layer 1: 256 -> 4x64 (f16 MFMA, fused elr) ----
    {
        dim3 grid(2, rowsP);
        gemm_l1<<<grid, 256, 0, stream>>>(hbf, wt1, featb, el, er, al1, ar1, N);
        agg4_kernel<4><<<(N + 7) / 8, 256, 0, stream>>>(featb, el, er, b1, cnt, csr, hbf, N);
    }
    // ---- Layer 2: 256 -> 1x16 (MFMA, W2 hi/lo split, fused elr) ----
    {
        gemm2_mfma<<<(N + 255) / 256, 256, 0, stream>>>(hbf, W2, al2, ar2, el, er, featb, N);
        agg16_kernel<64><<<(N + 3) / 4, 256, 0, stream>>>(featb, el, er, b2, cnt, csr, out, N);
    }
}